// Round 5
// baseline (65.318 us; speedup 1.0000x reference)
//
#include <hip/hip_runtime.h>

#define NB 512          // threads per block (8 waves)
#define APT 16          // atoms per thread (N = NB*APT = 8192)
#define NTYPE 11
#define CPAD 13         // padded per-thread counter row
#define NATOMS 8192
#define HALF 2048       // dst-range tile (four passes)
#define NPASS (NATOMS / HALF)

__global__ __launch_bounds__(NB, 8)
void typed_coords_kernel(const float* __restrict__ coords,
                         const int*   __restrict__ types,
                         const int*   __restrict__ num_atoms,
                         float* __restrict__ out,       // B*3N floats
                         float* __restrict__ out_cnt,   // B*NTYPE floats
                         float* __restrict__ out_off)   // B*NTYPE floats
{
    const int b    = blockIdx.x;
    const int tid  = threadIdx.x;
    const int lane = tid & 63;
    const int wave = tid >> 6;

    __shared__ float lds_half[HALF * 3];             // 24 KB dst-range tile
    __shared__ unsigned short lds_cnt[NB * CPAD];    // 13.3 KB counters
    __shared__ int lds_counts[NTYPE];
    __shared__ int lds_off[NTYPE];

    const int na     = num_atoms[b];
    const int base_i = tid * APT;

    // ---- load my 16 types into registers (skip fully-invalid tails) ----
    int ty[APT];
    const int* tptr = types + (size_t)b * NATOMS + base_i;
    if (base_i < na) {
        #pragma unroll
        for (int g = 0; g < APT / 4; ++g) {
            int4 v = *reinterpret_cast<const int4*>(tptr + g * 4);
            ty[g * 4 + 0] = v.x;
            ty[g * 4 + 1] = v.y;
            ty[g * 4 + 2] = v.z;
            ty[g * 4 + 3] = v.w;
        }
    }

    // ---- per-thread histogram in own LDS row ----
    #pragma unroll
    for (int t = 0; t < CPAD; ++t) lds_cnt[tid * CPAD + t] = 0;
    if (base_i < na) {
        #pragma unroll
        for (int k = 0; k < APT; ++k) {              // static indices only
            if (base_i + k < na) lds_cnt[tid * CPAD + ty[k]] += 1;
        }
    }
    __syncthreads();

    // ---- per-type exclusive scan across the 512 thread rows ----
    // wave w handles types w, w+8
    for (int tt = wave; tt < NTYPE; tt += NB / 64) {
        int run = 0;
        #pragma unroll
        for (int s = 0; s < NB / 64; ++s) {
            int idx = (s * 64 + lane) * CPAD + tt;
            int v = lds_cnt[idx];
            int x = v;
            #pragma unroll
            for (int d = 1; d < 64; d <<= 1) {
                int n = __shfl_up(x, d);
                if (lane >= d) x += n;
            }
            lds_cnt[idx] = (unsigned short)(x - v + run);  // exclusive prefix
            run += __shfl(x, 63);
        }
        lds_counts[tt] = run;
    }
    __syncthreads();

    // ---- type offsets (exclusive cumsum over 11 types) ----
    if (tid == 0) {
        int acc = 0;
        #pragma unroll
        for (int t = 0; t < NTYPE; ++t) { lds_off[t] = acc; acc += lds_counts[t]; }
    }
    __syncthreads();

    if (tid < NTYPE) {
        out_cnt[(size_t)b * NTYPE + tid] = (float)lds_counts[tid];
        out_off[(size_t)b * NTYPE + tid] = (float)lds_off[tid];
    }

    // ---- compute each atom's destination once; pack 2x16-bit per reg ----
    unsigned dpk[APT / 2];
    #pragma unroll
    for (int h = 0; h < APT / 2; ++h) dpk[h] = 0xFFFFFFFFu;
    if (base_i < na) {
        #pragma unroll
        for (int h = 0; h < APT / 2; ++h) {
            unsigned lo = 0xFFFFu, hi = 0xFFFFu;
            if (base_i + h * 2 + 0 < na) {
                int t = ty[h * 2 + 0];
                int idx = tid * CPAD + t;
                int r = lds_cnt[idx];
                lds_cnt[idx] = (unsigned short)(r + 1);
                lo = (unsigned)(lds_off[t] + r);
            }
            if (base_i + h * 2 + 1 < na) {
                int t = ty[h * 2 + 1];
                int idx = tid * CPAD + t;
                int r = lds_cnt[idx];
                lds_cnt[idx] = (unsigned short)(r + 1);
                hi = (unsigned)(lds_off[t] + r);
            }
            dpk[h] = lo | (hi << 16);
        }
    }

    // ---- four dst-range passes through the 24 KB tile ----
    const float* cbase = coords + (size_t)b * 3 * NATOMS;
    #pragma unroll 1
    for (int p = 0; p < NPASS; ++p) {
        if (p) __syncthreads();                      // prev writeout done

        // zero-fill invalid region of this tile
        int lo = na - p * HALF;
        if (lo < 0) lo = 0;
        if (lo > HALF) lo = HALF;
        for (int i = 3 * lo + tid; i < 3 * HALF; i += NB) lds_half[i] = 0.0f;

        // scatter my atoms whose dst falls in this range (predicated 12B loads)
        #pragma unroll
        for (int h = 0; h < APT / 2; ++h) {
            unsigned pk = dpk[h];
            int d0 = (int)(pk & 0xFFFFu) - p * HALF;
            int d1 = (int)(pk >> 16)     - p * HALF;
            if (d0 >= 0 && d0 < HALF) {              // sentinel lands out of range
                int i = base_i + h * 2 + 0;
                lds_half[d0 * 3 + 0] = cbase[i * 3 + 0];
                lds_half[d0 * 3 + 1] = cbase[i * 3 + 1];
                lds_half[d0 * 3 + 2] = cbase[i * 3 + 2];
            }
            if (d1 >= 0 && d1 < HALF) {
                int i = base_i + h * 2 + 1;
                lds_half[d1 * 3 + 0] = cbase[i * 3 + 0];
                lds_half[d1 * 3 + 1] = cbase[i * 3 + 1];
                lds_half[d1 * 3 + 2] = cbase[i * 3 + 2];
            }
        }
        __syncthreads();

        // fully-coalesced float4 writeout of this tile
        float4* o4 = reinterpret_cast<float4*>(
            out + (size_t)b * 3 * NATOMS + (size_t)p * HALF * 3);
        const float4* l4 = reinterpret_cast<const float4*>(lds_half);
        #pragma unroll
        for (int q = 0; q < (HALF * 3 / 4) / NB; ++q) {   // 3 iterations
            o4[q * NB + tid] = l4[q * NB + tid];
        }
    }
}

extern "C" void kernel_launch(void* const* d_in, const int* in_sizes, int n_in,
                              void* d_out, int out_size, void* d_ws, size_t ws_size,
                              hipStream_t stream) {
    const float* coords = (const float*)d_in[0];
    const int*   types  = (const int*)d_in[1];
    const int*   nums   = (const int*)d_in[2];
    const int B = in_sizes[2];            // num_atoms has B elements

    float* out     = (float*)d_out;
    float* out_cnt = out + (size_t)B * 3 * NATOMS;
    float* out_off = out_cnt + (size_t)B * NTYPE;

    typed_coords_kernel<<<B, NB, 0, stream>>>(coords, types, nums,
                                              out, out_cnt, out_off);
}

// Round 6
// 40.566 us; speedup vs baseline: 1.6102x; 1.6102x over previous
//
#include <hip/hip_runtime.h>

#define NB 512          // threads per block (8 waves)
#define APT 16          // atoms per thread (N = NB*APT = 8192)
#define NTYPE 11
#define CPAD 13         // padded per-thread counter row
#define NATOMS 8192
#define HALF 2048       // dst-range tile (four passes)
#define NPASS (NATOMS / HALF)

__global__ __launch_bounds__(NB, 6)   // VGPR cap 85 -> 3 blocks/CU (LDS allows 4)
void typed_coords_kernel(const float* __restrict__ coords,
                         const int*   __restrict__ types,
                         const int*   __restrict__ num_atoms,
                         float* __restrict__ out,       // B*3N floats
                         float* __restrict__ out_cnt,   // B*NTYPE floats
                         float* __restrict__ out_off)   // B*NTYPE floats
{
    const int b    = blockIdx.x;
    const int tid  = threadIdx.x;
    const int lane = tid & 63;
    const int wave = tid >> 6;

    __shared__ float lds_half[HALF * 3];             // 24 KB dst-range tile
    __shared__ unsigned short lds_cnt[NB * CPAD];    // 13.3 KB counters
    __shared__ int lds_counts[NTYPE];
    __shared__ int lds_off[NTYPE];

    const int na     = num_atoms[b];
    const int base_i = tid * APT;

    // ---- load my 16 types, pack 4 bits each into 2 uints ----
    unsigned tp0 = 0, tp1 = 0;
    {
        const int* tptr = types + (size_t)b * NATOMS + base_i;
        if (base_i < na) {
            int4 a = reinterpret_cast<const int4*>(tptr)[0];
            int4 c = reinterpret_cast<const int4*>(tptr)[1];
            int4 e = reinterpret_cast<const int4*>(tptr)[2];
            int4 g = reinterpret_cast<const int4*>(tptr)[3];
            tp0 = (unsigned)a.x | ((unsigned)a.y << 4) | ((unsigned)a.z << 8)  | ((unsigned)a.w << 12)
                | ((unsigned)c.x << 16) | ((unsigned)c.y << 20) | ((unsigned)c.z << 24) | ((unsigned)c.w << 28);
            tp1 = (unsigned)e.x | ((unsigned)e.y << 4) | ((unsigned)e.z << 8)  | ((unsigned)e.w << 12)
                | ((unsigned)g.x << 16) | ((unsigned)g.y << 20) | ((unsigned)g.z << 24) | ((unsigned)g.w << 28);
        }
    }
#define TYP(k) ((int)((((k) < 8 ? tp0 : tp1) >> (((k) & 7) * 4)) & 0xFu))

    // ---- issue coord loads into registers NOW; latency hides under scan ----
    float cf[APT * 3];
    {
        const float4* c4 = reinterpret_cast<const float4*>(
            coords + (size_t)b * 3 * NATOMS + (size_t)base_i * 3);  // 192B-aligned
        if (base_i < na) {
            #pragma unroll
            for (int g = 0; g < (APT * 3) / 4; ++g)
                *reinterpret_cast<float4*>(&cf[g * 4]) = c4[g];     // static idx
        } else {
            #pragma unroll
            for (int i = 0; i < APT * 3; ++i) cf[i] = 0.0f;
        }
    }

    // ---- per-thread histogram in own LDS row ----
    #pragma unroll
    for (int t = 0; t < CPAD; ++t) lds_cnt[tid * CPAD + t] = 0;
    if (base_i < na) {
        #pragma unroll
        for (int k = 0; k < APT; ++k) {              // static indices only
            if (base_i + k < na) lds_cnt[tid * CPAD + TYP(k)] += 1;
        }
    }
    __syncthreads();

    // ---- per-type exclusive scan across the 512 thread rows ----
    // wave w handles types w, w+8
    for (int tt = wave; tt < NTYPE; tt += NB / 64) {
        int run = 0;
        #pragma unroll
        for (int s = 0; s < NB / 64; ++s) {
            int idx = (s * 64 + lane) * CPAD + tt;
            int v = lds_cnt[idx];
            int x = v;
            #pragma unroll
            for (int d = 1; d < 64; d <<= 1) {
                int n = __shfl_up(x, d);
                if (lane >= d) x += n;
            }
            lds_cnt[idx] = (unsigned short)(x - v + run);  // exclusive prefix
            run += __shfl(x, 63);
        }
        lds_counts[tt] = run;
    }
    __syncthreads();

    // ---- type offsets (exclusive cumsum over 11 types) ----
    if (tid == 0) {
        int acc = 0;
        #pragma unroll
        for (int t = 0; t < NTYPE; ++t) { lds_off[t] = acc; acc += lds_counts[t]; }
    }
    __syncthreads();

    if (tid < NTYPE) {
        out_cnt[(size_t)b * NTYPE + tid] = (float)lds_counts[tid];
        out_off[(size_t)b * NTYPE + tid] = (float)lds_off[tid];
    }

    // ---- compute each atom's destination once; pack 2x16-bit per reg ----
    unsigned dpk[APT / 2];
    #pragma unroll
    for (int h = 0; h < APT / 2; ++h) dpk[h] = 0xFFFFFFFFu;
    if (base_i < na) {
        #pragma unroll
        for (int h = 0; h < APT / 2; ++h) {
            unsigned lo = 0xFFFFu, hi = 0xFFFFu;
            if (base_i + h * 2 + 0 < na) {
                int t = TYP(h * 2 + 0);
                int idx = tid * CPAD + t;
                int r = lds_cnt[idx];
                lds_cnt[idx] = (unsigned short)(r + 1);
                lo = (unsigned)(lds_off[t] + r);
            }
            if (base_i + h * 2 + 1 < na) {
                int t = TYP(h * 2 + 1);
                int idx = tid * CPAD + t;
                int r = lds_cnt[idx];
                lds_cnt[idx] = (unsigned short)(r + 1);
                hi = (unsigned)(lds_off[t] + r);
            }
            dpk[h] = lo | (hi << 16);
        }
    }

    // ---- pin coords in registers: forbid per-pass rematerialized reloads ----
    #pragma unroll
    for (int i = 0; i < APT * 3; ++i) asm volatile("" : "+v"(cf[i]));

    // ---- four dst-range passes through the 24 KB tile ----
    #pragma unroll 1
    for (int p = 0; p < NPASS; ++p) {
        if (p) __syncthreads();                      // prev writeout done

        // zero-fill invalid region of this tile
        int lo = na - p * HALF;
        if (lo < 0) lo = 0;
        if (lo > HALF) lo = HALF;
        for (int i = 3 * lo + tid; i < 3 * HALF; i += NB) lds_half[i] = 0.0f;

        // scatter my atoms whose dst falls in this range (registers only)
        #pragma unroll
        for (int h = 0; h < APT / 2; ++h) {
            unsigned pk = dpk[h];
            int d0 = (int)(pk & 0xFFFFu) - p * HALF;
            int d1 = (int)(pk >> 16)     - p * HALF;
            if (d0 >= 0 && d0 < HALF) {              // sentinel lands out of range
                lds_half[d0 * 3 + 0] = cf[(h * 2 + 0) * 3 + 0];
                lds_half[d0 * 3 + 1] = cf[(h * 2 + 0) * 3 + 1];
                lds_half[d0 * 3 + 2] = cf[(h * 2 + 0) * 3 + 2];
            }
            if (d1 >= 0 && d1 < HALF) {
                lds_half[d1 * 3 + 0] = cf[(h * 2 + 1) * 3 + 0];
                lds_half[d1 * 3 + 1] = cf[(h * 2 + 1) * 3 + 1];
                lds_half[d1 * 3 + 2] = cf[(h * 2 + 1) * 3 + 2];
            }
        }
        __syncthreads();

        // fully-coalesced float4 writeout of this tile
        float4* o4 = reinterpret_cast<float4*>(
            out + (size_t)b * 3 * NATOMS + (size_t)p * HALF * 3);
        const float4* l4 = reinterpret_cast<const float4*>(lds_half);
        #pragma unroll
        for (int q = 0; q < (HALF * 3 / 4) / NB; ++q) {   // 3 iterations
            o4[q * NB + tid] = l4[q * NB + tid];
        }
    }
#undef TYP
}

extern "C" void kernel_launch(void* const* d_in, const int* in_sizes, int n_in,
                              void* d_out, int out_size, void* d_ws, size_t ws_size,
                              hipStream_t stream) {
    const float* coords = (const float*)d_in[0];
    const int*   types  = (const int*)d_in[1];
    const int*   nums   = (const int*)d_in[2];
    const int B = in_sizes[2];            // num_atoms has B elements

    float* out     = (float*)d_out;
    float* out_cnt = out + (size_t)B * 3 * NATOMS;
    float* out_off = out_cnt + (size_t)B * NTYPE;

    typed_coords_kernel<<<B, NB, 0, stream>>>(coords, types, nums,
                                              out, out_cnt, out_off);
}

// Round 7
// 39.863 us; speedup vs baseline: 1.6386x; 1.0176x over previous
//
#include <hip/hip_runtime.h>

#define NB 512          // threads per block (8 waves)
#define APT 16          // atoms per thread (N = NB*APT = 8192)
#define NTYPE 11
#define CPAD 13         // padded per-thread counter row
#define NATOMS 8192
#define HALF 2048       // dst-range tile (four passes)
#define NPASS (NATOMS / HALF)

__global__ __launch_bounds__(NB, 6)   // VGPR cap 85; LDS 38KB -> 3 blocks/CU
void typed_coords_kernel(const float* __restrict__ coords,
                         const int*   __restrict__ types,
                         const int*   __restrict__ num_atoms,
                         float* __restrict__ out,       // B*3N floats
                         float* __restrict__ out_cnt,   // B*NTYPE floats
                         float* __restrict__ out_off)   // B*NTYPE floats
{
    const int b    = blockIdx.x;
    const int tid  = threadIdx.x;
    const int lane = tid & 63;
    const int wave = tid >> 6;

    __shared__ float lds_half[HALF * 3];             // 24 KB dst-range tile
    __shared__ unsigned short lds_cnt[NB * CPAD];    // 13.3 KB counters/bases
    __shared__ int lds_counts[NTYPE];
    __shared__ int lds_off[NTYPE];

    const int na     = num_atoms[b];
    const int base_i = tid * APT;

    // ---- load my 16 types, pack 4 bits each into 2 uints ----
    unsigned tp0 = 0, tp1 = 0;
    {
        const int* tptr = types + (size_t)b * NATOMS + base_i;
        if (base_i < na) {
            int4 a = reinterpret_cast<const int4*>(tptr)[0];
            int4 c = reinterpret_cast<const int4*>(tptr)[1];
            int4 e = reinterpret_cast<const int4*>(tptr)[2];
            int4 g = reinterpret_cast<const int4*>(tptr)[3];
            tp0 = (unsigned)a.x | ((unsigned)a.y << 4) | ((unsigned)a.z << 8)  | ((unsigned)a.w << 12)
                | ((unsigned)c.x << 16) | ((unsigned)c.y << 20) | ((unsigned)c.z << 24) | ((unsigned)c.w << 28);
            tp1 = (unsigned)e.x | ((unsigned)e.y << 4) | ((unsigned)e.z << 8)  | ((unsigned)e.w << 12)
                | ((unsigned)g.x << 16) | ((unsigned)g.y << 20) | ((unsigned)g.z << 24) | ((unsigned)g.w << 28);
        }
    }
#define TYP(k) ((int)((((k) < 8 ? tp0 : tp1) >> (((k) & 7) * 4)) & 0xFu))

    // ---- issue coord loads into registers NOW; latency hides under scan ----
    float cf[APT * 3];
    {
        const float4* c4 = reinterpret_cast<const float4*>(
            coords + (size_t)b * 3 * NATOMS + (size_t)base_i * 3);  // 192B-aligned
        if (base_i < na) {
            #pragma unroll
            for (int g = 0; g < (APT * 3) / 4; ++g)
                *reinterpret_cast<float4*>(&cf[g * 4]) = c4[g];     // static idx
        } else {
            #pragma unroll
            for (int i = 0; i < APT * 3; ++i) cf[i] = 0.0f;
        }
    }

    // ---- per-thread histogram in REGISTERS: 11 x 5-bit fields in 3 uints ----
    unsigned h0 = 0, h1 = 0, h2 = 0;
    if (base_i < na) {
        #pragma unroll
        for (int k = 0; k < APT; ++k) {              // static indices only
            if (base_i + k < na) {
                int t = TYP(k);
                int g = t >> 2;
                unsigned inc = 1u << ((t & 3) * 5);
                h0 += (g == 0) ? inc : 0u;
                h1 += (g == 1) ? inc : 0u;
                h2 += (g == 2) ? inc : 0u;
            }
        }
    }
    // write 11 counts with independent 16-bit stores (no dependent chain)
    #pragma unroll
    for (int t = 0; t < NTYPE; ++t) {                // t compile-time
        unsigned r = ((t >> 2) == 0) ? h0 : (((t >> 2) == 1) ? h1 : h2);
        lds_cnt[tid * CPAD + t] = (unsigned short)((r >> ((t & 3) * 5)) & 31u);
    }
    __syncthreads();

    // ---- per-type exclusive scan across the 512 thread rows ----
    // wave w handles types w, w+8
    for (int tt = wave; tt < NTYPE; tt += NB / 64) {
        int run = 0;
        #pragma unroll
        for (int s = 0; s < NB / 64; ++s) {
            int idx = (s * 64 + lane) * CPAD + tt;
            int v = lds_cnt[idx];
            int x = v;
            #pragma unroll
            for (int d = 1; d < 64; d <<= 1) {
                int n = __shfl_up(x, d);
                if (lane >= d) x += n;
            }
            lds_cnt[idx] = (unsigned short)(x - v + run);  // exclusive prefix
            run += __shfl(x, 63);
        }
        lds_counts[tt] = run;
    }
    __syncthreads();

    // ---- type offsets (exclusive cumsum over 11 types) ----
    if (tid == 0) {
        int acc = 0;
        #pragma unroll
        for (int t = 0; t < NTYPE; ++t) { lds_off[t] = acc; acc += lds_counts[t]; }
    }
    __syncthreads();

    if (tid < NTYPE) {
        out_cnt[(size_t)b * NTYPE + tid] = (float)lds_counts[tid];
        out_off[(size_t)b * NTYPE + tid] = (float)lds_off[tid];
    }

    // ---- dst per atom: rank from register counters + independent base read ----
    unsigned dpk[APT / 2];
    #pragma unroll
    for (int h = 0; h < APT / 2; ++h) dpk[h] = 0xFFFFFFFFu;
    h0 = 0; h1 = 0; h2 = 0;
    if (base_i < na) {
        #pragma unroll
        for (int h = 0; h < APT / 2; ++h) {
            unsigned lo = 0xFFFFu, hi = 0xFFFFu;
            #pragma unroll
            for (int j = 0; j < 2; ++j) {            // j compile-time
                int k = h * 2 + j;
                if (base_i + k < na) {
                    int t  = TYP(k);
                    int g  = t >> 2;
                    int sh = (t & 3) * 5;
                    unsigned cur  = (g == 0) ? h0 : ((g == 1) ? h1 : h2);
                    unsigned rank = (cur >> sh) & 31u;
                    unsigned base = lds_cnt[tid * CPAD + t];   // pure read
                    unsigned d    = (unsigned)lds_off[t] + base + rank;
                    unsigned inc  = 1u << sh;
                    h0 += (g == 0) ? inc : 0u;
                    h1 += (g == 1) ? inc : 0u;
                    h2 += (g == 2) ? inc : 0u;
                    if (j == 0) lo = d; else hi = d;
                }
            }
            dpk[h] = lo | (hi << 16);
        }
    }

    // ---- pin coords in registers: forbid per-pass rematerialized reloads ----
    #pragma unroll
    for (int i = 0; i < APT * 3; ++i) asm volatile("" : "+v"(cf[i]));

    // ---- four dst-range passes ----
    #pragma unroll 1
    for (int p = 0; p < NPASS; ++p) {
        if (p) __syncthreads();                      // prev writeout done

        float4* o4 = reinterpret_cast<float4*>(
            out + (size_t)b * 3 * NATOMS + (size_t)p * HALF * 3);

        if (na <= p * HALF) {
            // whole tile is zeros: stream directly, no LDS round-trip
            float4 z = make_float4(0.f, 0.f, 0.f, 0.f);
            #pragma unroll
            for (int q = 0; q < (HALF * 3 / 4) / NB; ++q)   // 3 stores
                o4[q * NB + tid] = z;
            continue;                                // uniform branch
        }

        // zero-fill invalid region of this tile
        int lo = na - p * HALF;
        if (lo < 0) lo = 0;
        if (lo > HALF) lo = HALF;
        for (int i = 3 * lo + tid; i < 3 * HALF; i += NB) lds_half[i] = 0.0f;

        // scatter my atoms whose dst falls in this range (registers only)
        #pragma unroll
        for (int h = 0; h < APT / 2; ++h) {
            unsigned pk = dpk[h];
            int d0 = (int)(pk & 0xFFFFu) - p * HALF;
            int d1 = (int)(pk >> 16)     - p * HALF;
            if (d0 >= 0 && d0 < HALF) {              // sentinel lands out of range
                lds_half[d0 * 3 + 0] = cf[(h * 2 + 0) * 3 + 0];
                lds_half[d0 * 3 + 1] = cf[(h * 2 + 0) * 3 + 1];
                lds_half[d0 * 3 + 2] = cf[(h * 2 + 0) * 3 + 2];
            }
            if (d1 >= 0 && d1 < HALF) {
                lds_half[d1 * 3 + 0] = cf[(h * 2 + 1) * 3 + 0];
                lds_half[d1 * 3 + 1] = cf[(h * 2 + 1) * 3 + 1];
                lds_half[d1 * 3 + 2] = cf[(h * 2 + 1) * 3 + 2];
            }
        }
        __syncthreads();

        // fully-coalesced float4 writeout of this tile
        const float4* l4 = reinterpret_cast<const float4*>(lds_half);
        #pragma unroll
        for (int q = 0; q < (HALF * 3 / 4) / NB; ++q) {   // 3 iterations
            o4[q * NB + tid] = l4[q * NB + tid];
        }
    }
#undef TYP
}

extern "C" void kernel_launch(void* const* d_in, const int* in_sizes, int n_in,
                              void* d_out, int out_size, void* d_ws, size_t ws_size,
                              hipStream_t stream) {
    const float* coords = (const float*)d_in[0];
    const int*   types  = (const int*)d_in[1];
    const int*   nums   = (const int*)d_in[2];
    const int B = in_sizes[2];            // num_atoms has B elements

    float* out     = (float*)d_out;
    float* out_cnt = out + (size_t)B * 3 * NATOMS;
    float* out_off = out_cnt + (size_t)B * NTYPE;

    typed_coords_kernel<<<B, NB, 0, stream>>>(coords, types, nums,
                                              out, out_cnt, out_off);
}